// Round 13
// baseline (493.730 us; speedup 1.0000x reference)
//
#include <hip/hip_runtime.h>
#include <math.h>

#define KC 3
#define S 12
#define SS 1728
#define AB 32
#define TLEN 64
#define NTHREADS 896
#define NWAVES 14
#define NACT 864            // 432 slices x 2 threads; 864*2 = 1728 = SS slots
#define LN2F 0.69314718055994530942f

__global__ __launch_bounds__(NTHREADS, 2)
void hmm_fwd_kernel(const int* __restrict__ ys,
                    const float* __restrict__ transition,  // [3][12][12]
                    const float* __restrict__ emission,    // [3][12][32]
                    const float* __restrict__ choice,      // [3]
                    const float* __restrict__ prior,       // [3][12]
                    float* __restrict__ out)
{
    // G = beta buffers (natural order n = 144 s0 + 12 s1 + s2), triple-buffered:
    // read G[cur], atomically accumulate next beta into G[nxt], zero G[zro].
    __shared__ __align__(16) float G[KC][SS];
    __shared__ __align__(16) float ECt[KC][AB][16];  // [k][y][slot], slot=(j/6)*8+j%6
    __shared__ __align__(16) float T_s[KC][S][16];   // [k][i][slot]
    __shared__ float p_lin[KC][S];
    __shared__ int   ys_s[TLEN];
    __shared__ float wsum[NWAVES];

    const int tid = threadIdx.x;

    // ---------------- setup: linear-space tables ----------------
    if (tid < TLEN) ys_s[tid] = ys[tid];

    if (tid >= 1 && tid < 1 + KC) {
        int k = tid - 1;
        float m = -INFINITY;
        #pragma unroll
        for (int i = 0; i < S; ++i) m = fmaxf(m, prior[k*S + i]);
        float ev[S]; float s = 0.f;
        #pragma unroll
        for (int i = 0; i < S; ++i) { ev[i] = __expf(prior[k*S + i] - m); s += ev[i]; }
        float inv = 1.f / s;
        #pragma unroll
        for (int i = 0; i < S; ++i) p_lin[k][i] = ev[i] * inv;
    }
    if (tid >= 64 && tid < 64 + KC*S) {      // transition -> softmax probs, padded rows
        int r = tid - 64;
        int k = r / S, i = r % S;
        const float* row = transition + (k*S + i)*S;
        float m = -INFINITY;
        #pragma unroll
        for (int j = 0; j < S; ++j) m = fmaxf(m, row[j]);
        float ev[S]; float s = 0.f;
        #pragma unroll
        for (int j = 0; j < S; ++j) { ev[j] = __expf(row[j] - m); s += ev[j]; }
        float inv = 1.f / s;
        #pragma unroll
        for (int j = 0; j < S; ++j) T_s[k][i][(j/6)*8 + (j%6)] = ev[j] * inv;
    }
    if (tid >= 128 && tid < 128 + KC*S) {    // emission -> ECt = C[k]*softmax, padded
        int r = tid - 128;
        int k = r / S, sj = r % S;
        float cm = fmaxf(fmaxf(choice[0], choice[1]), choice[2]);
        float ce = __expf(choice[k]-cm) /
                   (__expf(choice[0]-cm) + __expf(choice[1]-cm) + __expf(choice[2]-cm));
        const float* row = emission + (k*S + sj)*AB;
        float m = -INFINITY;
        #pragma unroll
        for (int a = 0; a < AB; ++a) m = fmaxf(m, row[a]);
        float ev[AB]; float s = 0.f;
        #pragma unroll
        for (int a = 0; a < AB; ++a) { ev[a] = __expf(row[a] - m); s += ev[a]; }
        float inv = ce / s;
        const int slot = (sj / 6) * 8 + (sj % 6);
        #pragma unroll
        for (int a = 0; a < AB; ++a) ECt[k][a][slot] = ev[a] * inv;
    }
    __syncthreads();

    // ---------------- per-thread statics ----------------
    const bool act = tid < NACT;
    const int ct = act ? tid : (NACT - 1);
    const int sl = ct >> 1;            // slice 0..431
    const int h  = ct & 1;             // output half: columns 6h..6h+5
    const int sk = sl / 144;           // chain
    const int q  = sl % 144;
    const int qh = q / 12, ql = q % 12;

    // gather base (natural order) + stride per chain
    const int rdb  = (sk == 0) ? q : (sk == 1) ? 144*qh + ql : 12*q;
    const int wstr = (sk == 0) ? 144 : (sk == 1) ? 12 : 1;
    // atomic-accumulate target indices (j = 6h + m)
    const int wi0 = rdb + wstr*(6*h + 0), wi1 = rdb + wstr*(6*h + 1);
    const int wi2 = rdb + wstr*(6*h + 2), wi3 = rdb + wstr*(6*h + 3);
    const int wi4 = rdb + wstr*(6*h + 4), wi5 = rdb + wstr*(6*h + 5);

    const float* const ecp = &ECt[sk][0][8*h];
    const float* const tbp = &T_s[sk][0][8*h];
    const int s2p = 2 * ct;            // this thread's 2 owned beta slots

    // init: G[0][n] = prior product (sum_k alpha0 = prod * sum_k c = prod);
    //       G[1] zeroed (accumulate target of step 0)
    if (act) {
        const int a0 = s2p/144, b0 = (s2p/12)%12, c0 = s2p%12;   // c0 even
        const float pp = p_lin[0][a0] * p_lin[1][b0];
        float2 v; v.x = pp * p_lin[2][c0]; v.y = pp * p_lin[2][c0+1];
        *reinterpret_cast<float2*>(&G[0][s2p]) = v;
        *reinterpret_cast<float2*>(&G[1][s2p]) = make_float2(0.f, 0.f);
    }
    __syncthreads();

    // ---------------- 64 steps, ONE barrier each ----------------
    float logR = 0.f, invR = 1.f;
    float* gc = &G[0][0];   // read
    float* gn = &G[1][0];   // accumulate (zeroed)
    float* gz = &G[2][0];   // zero now, accumulate next step

    #pragma unroll 1
    for (int t = 0; t < TLEN; ++t) {
        const int y = ys_s[t];
        float o0=0.f,o1=0.f,o2=0.f,o3=0.f,o4=0.f,o5=0.f;

        if (act) {
            // zero the buffer used as accumulate-target next step
            *reinterpret_cast<float2*>(&gz[s2p]) = make_float2(0.f, 0.f);

            // E half-row (broadcast)
            float4 e03 = *reinterpret_cast<const float4*>(&ecp[y*16]);
            float2 e45 = *reinterpret_cast<const float2*>(&ecp[y*16 + 4]);

            // gather 12 betas from G[cur]
            float bv0,bv1,bv2,bv3,bv4,bv5,bv6,bv7,bv8,bv9,bv10,bv11;
            if (sk == 0) {
                bv0=gc[rdb+0*144]; bv1=gc[rdb+1*144]; bv2 =gc[rdb+2*144];  bv3 =gc[rdb+3*144];
                bv4=gc[rdb+4*144]; bv5=gc[rdb+5*144]; bv6 =gc[rdb+6*144];  bv7 =gc[rdb+7*144];
                bv8=gc[rdb+8*144]; bv9=gc[rdb+9*144]; bv10=gc[rdb+10*144]; bv11=gc[rdb+11*144];
            } else if (sk == 1) {
                bv0=gc[rdb+0*12]; bv1=gc[rdb+1*12]; bv2 =gc[rdb+2*12];  bv3 =gc[rdb+3*12];
                bv4=gc[rdb+4*12]; bv5=gc[rdb+5*12]; bv6 =gc[rdb+6*12];  bv7 =gc[rdb+7*12];
                bv8=gc[rdb+8*12]; bv9=gc[rdb+9*12]; bv10=gc[rdb+10*12]; bv11=gc[rdb+11*12];
            } else {
                float4 r0 = *reinterpret_cast<const float4*>(&gc[rdb + 0]);
                float4 r1 = *reinterpret_cast<const float4*>(&gc[rdb + 4]);
                float4 r2 = *reinterpret_cast<const float4*>(&gc[rdb + 8]);
                bv0=r0.x; bv1=r0.y; bv2 =r0.z; bv3 =r0.w;
                bv4=r1.x; bv5=r1.y; bv6 =r1.z; bv7 =r1.w;
                bv8=r2.x; bv9=r2.y; bv10=r2.z; bv11=r2.w;
            }

            // 12 T rows (broadcast b128+b64) x 6 FMA each
            float a0=0.f,a1=0.f,a2=0.f,a3=0.f,a4=0.f,a5=0.f;
            #pragma unroll
            for (int i = 0; i < S; ++i) {
                float4 t03 = *reinterpret_cast<const float4*>(&tbp[16*i]);
                float2 t45 = *reinterpret_cast<const float2*>(&tbp[16*i + 4]);
                const float bb = (i==0)?bv0:(i==1)?bv1:(i==2)?bv2:(i==3)?bv3:
                                 (i==4)?bv4:(i==5)?bv5:(i==6)?bv6:(i==7)?bv7:
                                 (i==8)?bv8:(i==9)?bv9:(i==10)?bv10:bv11;
                a0 = __builtin_fmaf(bb, t03.x, a0);
                a1 = __builtin_fmaf(bb, t03.y, a1);
                a2 = __builtin_fmaf(bb, t03.z, a2);
                a3 = __builtin_fmaf(bb, t03.w, a3);
                a4 = __builtin_fmaf(bb, t45.x, a4);
                a5 = __builtin_fmaf(bb, t45.y, a5);
            }
            o0 = a0*e03.x*invR; o1 = a1*e03.y*invR; o2 = a2*e03.z*invR;
            o3 = a3*e03.w*invR; o4 = a4*e45.x*invR; o5 = a5*e45.y*invR;

            // accumulate contributions into next beta (ds_add_f32)
            atomicAdd(&gn[wi0], o0); atomicAdd(&gn[wi1], o1);
            atomicAdd(&gn[wi2], o2); atomicAdd(&gn[wi3], o3);
            atomicAdd(&gn[wi4], o4); atomicAdd(&gn[wi5], o5);
        }

        if ((t & 7) == 7) {
            float part = o0 + o1 + o2 + o3 + o4 + o5;   // 0 for inactive
            part += __shfl_xor(part, 32); part += __shfl_xor(part, 16);
            part += __shfl_xor(part, 8);  part += __shfl_xor(part, 4);
            part += __shfl_xor(part, 2);  part += __shfl_xor(part, 1);
            if ((tid & 63) == 0) wsum[tid >> 6] = part;
        }
        __syncthreads();   // single barrier: G[nxt] complete, wsum visible

        if ((t & 7) == 7 && t < TLEN-1) {
            float R = 0.f;
            #pragma unroll
            for (int w = 0; w < NWAVES; ++w) R += wsum[w];
            invR = __builtin_amdgcn_rcpf(R);
            logR += __log2f(R);
        } else {
            invR = 1.f;
        }

        // rotate buffers
        float* tmp = gc; gc = gn; gn = gz; gz = tmp;
    }

    // final: total mass at t=63 is in wsum (its normalizer never applied)
    if (tid == 0) {
        float R = 0.f;
        #pragma unroll
        for (int w = 0; w < NWAVES; ++w) R += wsum[w];
        out[0] = LN2F * (__log2f(R) + logR);
    }
}

extern "C" void kernel_launch(void* const* d_in, const int* in_sizes, int n_in,
                              void* d_out, int out_size, void* d_ws, size_t ws_size,
                              hipStream_t stream) {
    const int*   ys         = (const int*)  d_in[0];
    const float* transition = (const float*)d_in[1];
    const float* emission   = (const float*)d_in[2];
    const float* choice     = (const float*)d_in[3];
    const float* prior      = (const float*)d_in[4];
    float* out = (float*)d_out;

    hipLaunchKernelGGL(hmm_fwd_kernel, dim3(1), dim3(NTHREADS), 0, stream,
                       ys, transition, emission, choice, prior, out);
}

// Round 14
// 74.375 us; speedup vs baseline: 6.6384x; 6.6384x over previous
//
#include <hip/hip_runtime.h>
#include <math.h>

#define KC 3
#define S 12
#define SS 1728
#define AB 32
#define TLEN 64
#define NTHREADS 448
#define NWAVES 7
#define NACT 432            // each thread owns 4 contiguous states: n = 4*tid
#define LN2F 0.69314718055994530942f

__global__ __launch_bounds__(NTHREADS, 2)
void hmm_fwd_kernel(const int* __restrict__ ys,
                    const float* __restrict__ transition,  // [3][12][12]
                    const float* __restrict__ emission,    // [3][12][32]
                    const float* __restrict__ choice,      // [3]
                    const float* __restrict__ prior,       // [3][12]
                    float* __restrict__ out)
{
    // beta ping-pong, natural order n = 144 s0 + 12 s1 + s2
    __shared__ __align__(16) float B[2][SS];
    // y-dependent fused matrices, 144 floats per y:
    //   M2 [y][i][j]  = T2[i][j]*EC2[j][y]   (row-major)
    //   M1T[y][j][i]  = T1[i][j]*EC1[j][y]   (transposed)
    //   M0T[y][j][i]  = T0[i][j]*EC0[j][y]   (transposed)
    __shared__ __align__(16) float M2[AB*144];
    __shared__ __align__(16) float M1T[AB*144];
    __shared__ __align__(16) float M0T[AB*144];
    __shared__ float T_s[KC][S][S];
    __shared__ float ECt[KC][AB][S];   // C[k]*softmax(emission[k][j])[y] at [k][y][j]
    __shared__ float p_lin[KC][S];
    __shared__ int   ys_s[TLEN];
    __shared__ float wsum[NWAVES];

    const int tid = threadIdx.x;

    // ---------------- setup 1: linear-space base tables ----------------
    if (tid < TLEN) ys_s[tid] = ys[tid];

    if (tid >= 1 && tid < 1 + KC) {
        int k = tid - 1;
        float m = -INFINITY;
        #pragma unroll
        for (int i = 0; i < S; ++i) m = fmaxf(m, prior[k*S + i]);
        float ev[S]; float s = 0.f;
        #pragma unroll
        for (int i = 0; i < S; ++i) { ev[i] = __expf(prior[k*S + i] - m); s += ev[i]; }
        float inv = 1.f / s;
        #pragma unroll
        for (int i = 0; i < S; ++i) p_lin[k][i] = ev[i] * inv;
    }
    if (tid >= 64 && tid < 64 + KC*S) {      // transition -> softmax probs
        int r = tid - 64;
        int k = r / S, i = r % S;
        const float* row = transition + (k*S + i)*S;
        float m = -INFINITY;
        #pragma unroll
        for (int j = 0; j < S; ++j) m = fmaxf(m, row[j]);
        float ev[S]; float s = 0.f;
        #pragma unroll
        for (int j = 0; j < S; ++j) { ev[j] = __expf(row[j] - m); s += ev[j]; }
        float inv = 1.f / s;
        #pragma unroll
        for (int j = 0; j < S; ++j) T_s[k][i][j] = ev[j] * inv;
    }
    if (tid >= 128 && tid < 128 + KC*S) {    // emission -> ECt[k][y][j] = C[k]*softmax
        int r = tid - 128;
        int k = r / S, sj = r % S;
        float cm = fmaxf(fmaxf(choice[0], choice[1]), choice[2]);
        float ce = __expf(choice[k]-cm) /
                   (__expf(choice[0]-cm) + __expf(choice[1]-cm) + __expf(choice[2]-cm));
        const float* row = emission + (k*S + sj)*AB;
        float m = -INFINITY;
        #pragma unroll
        for (int a = 0; a < AB; ++a) m = fmaxf(m, row[a]);
        float ev[AB]; float s = 0.f;
        #pragma unroll
        for (int a = 0; a < AB; ++a) { ev[a] = __expf(row[a] - m); s += ev[a]; }
        float inv = ce / s;
        #pragma unroll
        for (int a = 0; a < AB; ++a) ECt[k][a][sj] = ev[a] * inv;
    }
    __syncthreads();

    // ---------------- setup 2: fused M tables + beta init ----------------
    if (tid < 96) {                          // one (k,y) pair per thread
        const int k = tid >> 5, y = tid & 31;
        float* dst = (k == 2) ? &M2[y*144] : (k == 1) ? &M1T[y*144] : &M0T[y*144];
        if (k == 2) {
            #pragma unroll
            for (int i = 0; i < S; ++i)
                #pragma unroll
                for (int j = 0; j < S; ++j)
                    dst[i*12 + j] = T_s[2][i][j] * ECt[2][y][j];
        } else {
            #pragma unroll
            for (int j = 0; j < S; ++j)
                #pragma unroll
                for (int i = 0; i < S; ++i)
                    dst[j*12 + i] = T_s[k][i][j] * ECt[k][y][j];
        }
    }

    const bool act = tid < NACT;
    const int ct  = act ? tid : (NACT - 1);
    const int n   = 4 * ct;
    const int s0  = n / 144, s1 = (n / 12) % 12, s2b = n % 12;  // s2b in {0,4,8}
    const int rowb  = 144*s0 + 12*s1;        // axis-2 beta row base
    const int ax1b  = 144*s0 + s2b;          // axis-1 beta gather base (+12i)
    const int ax0b  = 12*s1  + s2b;          // axis-0 beta gather base (+144i)
    const int m1off = 12*s1;
    const int m0off = 12*s0;

    if (act) {                               // beta0[s] = p0[s0] p1[s1] p2[s2]
        const float pp = p_lin[0][s0] * p_lin[1][s1];
        float4 v;
        v.x = pp * p_lin[2][s2b+0]; v.y = pp * p_lin[2][s2b+1];
        v.z = pp * p_lin[2][s2b+2]; v.w = pp * p_lin[2][s2b+3];
        *reinterpret_cast<float4*>(&B[0][n]) = v;
    }
    __syncthreads();

    // ---------------- 64 steps, ONE barrier each ----------------
    float logR = 0.f, invR = 1.f;
    int yc = ys_s[0];

    #pragma unroll 1
    for (int t = 0; t < TLEN; ++t) {
        float o0 = 0.f, o1 = 0.f, o2 = 0.f, o3 = 0.f;

        if (act) {
            const float* bc = (t & 1) ? &B[1][0] : &B[0][0];
            float*       bn = (t & 1) ? &B[0][0] : &B[1][0];
            const int yb = yc * 144;

            // per-lane M vectors (axis-1: 2-way; axis-0: near-broadcast)
            float mv1[S], mv0[S];
            *reinterpret_cast<float4*>(&mv1[0]) = *reinterpret_cast<const float4*>(&M1T[yb + m1off + 0]);
            *reinterpret_cast<float4*>(&mv1[4]) = *reinterpret_cast<const float4*>(&M1T[yb + m1off + 4]);
            *reinterpret_cast<float4*>(&mv1[8]) = *reinterpret_cast<const float4*>(&M1T[yb + m1off + 8]);
            *reinterpret_cast<float4*>(&mv0[0]) = *reinterpret_cast<const float4*>(&M0T[yb + m0off + 0]);
            *reinterpret_cast<float4*>(&mv0[4]) = *reinterpret_cast<const float4*>(&M0T[yb + m0off + 4]);
            *reinterpret_cast<float4*>(&mv0[8]) = *reinterpret_cast<const float4*>(&M0T[yb + m0off + 8]);

            // axis-2: own beta row (12 floats) x M2 column block
            float r2[S];
            *reinterpret_cast<float4*>(&r2[0]) = *reinterpret_cast<const float4*>(&bc[rowb + 0]);
            *reinterpret_cast<float4*>(&r2[4]) = *reinterpret_cast<const float4*>(&bc[rowb + 4]);
            *reinterpret_cast<float4*>(&r2[8]) = *reinterpret_cast<const float4*>(&bc[rowb + 8]);

            float a0 = 0.f, a1 = 0.f, a2 = 0.f, a3 = 0.f;
            #pragma unroll
            for (int i = 0; i < S; ++i) {
                float4 m2 = *reinterpret_cast<const float4*>(&M2[yb + 12*i + s2b]);
                const float r = r2[i];
                a0 = __builtin_fmaf(r, m2.x, a0);
                a1 = __builtin_fmaf(r, m2.y, a1);
                a2 = __builtin_fmaf(r, m2.z, a2);
                a3 = __builtin_fmaf(r, m2.w, a3);
            }
            // axis-1: beta[(s0, i, s2b+e)] (multicast) x mv1[i]
            #pragma unroll
            for (int i = 0; i < S; ++i) {
                float4 b4 = *reinterpret_cast<const float4*>(&bc[ax1b + 12*i]);
                const float m = mv1[i];
                a0 = __builtin_fmaf(b4.x, m, a0);
                a1 = __builtin_fmaf(b4.y, m, a1);
                a2 = __builtin_fmaf(b4.z, m, a2);
                a3 = __builtin_fmaf(b4.w, m, a3);
            }
            // axis-0: beta[(i, s1, s2b+e)] x mv0[i]
            #pragma unroll
            for (int i = 0; i < S; ++i) {
                float4 b4 = *reinterpret_cast<const float4*>(&bc[ax0b + 144*i]);
                const float m = mv0[i];
                a0 = __builtin_fmaf(b4.x, m, a0);
                a1 = __builtin_fmaf(b4.y, m, a1);
                a2 = __builtin_fmaf(b4.z, m, a2);
                a3 = __builtin_fmaf(b4.w, m, a3);
            }

            o0 = a0 * invR; o1 = a1 * invR; o2 = a2 * invR; o3 = a3 * invR;
            *reinterpret_cast<float4*>(&bn[n]) = make_float4(o0, o1, o2, o3);
        }

        yc = ys_s[(t + 1) & (TLEN - 1)];     // prefetch next step's symbol

        if ((t & 7) == 7) {
            float part = o0 + o1 + o2 + o3;  // 0 for inactive threads
            part += __shfl_xor(part, 32); part += __shfl_xor(part, 16);
            part += __shfl_xor(part, 8);  part += __shfl_xor(part, 4);
            part += __shfl_xor(part, 2);  part += __shfl_xor(part, 1);
            if ((tid & 63) == 0) wsum[tid >> 6] = part;
        }
        __syncthreads();                     // single barrier per step

        if ((t & 7) == 7 && t < TLEN - 1) {
            float R = wsum[0]+wsum[1]+wsum[2]+wsum[3]+wsum[4]+wsum[5]+wsum[6];
            invR = __builtin_amdgcn_rcpf(R);
            logR += __log2f(R);
        } else {
            invR = 1.f;
        }
    }

    // final: total mass at t=63 (its normalizer never applied) is in wsum
    if (tid == 0) {
        float R = wsum[0]+wsum[1]+wsum[2]+wsum[3]+wsum[4]+wsum[5]+wsum[6];
        out[0] = LN2F * (__log2f(R) + logR);
    }
}

extern "C" void kernel_launch(void* const* d_in, const int* in_sizes, int n_in,
                              void* d_out, int out_size, void* d_ws, size_t ws_size,
                              hipStream_t stream) {
    const int*   ys         = (const int*)  d_in[0];
    const float* transition = (const float*)d_in[1];
    const float* emission   = (const float*)d_in[2];
    const float* choice     = (const float*)d_in[3];
    const float* prior      = (const float*)d_in[4];
    float* out = (float*)d_out;

    hipLaunchKernelGGL(hmm_fwd_kernel, dim3(1), dim3(NTHREADS), 0, stream,
                       ys, transition, emission, choice, prior, out);
}